// Round 1
// baseline (553.203 us; speedup 1.0000x reference)
//
#include <hip/hip_runtime.h>

#define NUM_LEVELS 16
#define LOG2_HASHMAP 19
#define TABLE_SIZE (1u << LOG2_HASHMAP)

// One thread per (point, level). tid = point*16 + level.
// - Output store: out2[n*16 + l] -> consecutive lanes write consecutive
//   float2s (512 B contiguous per wave), fully coalesced.
// - Each thread does one independent 8B gather from its level's table;
//   32M threads of TLP hide random-access latency (tables = 64 MB, mostly
//   L2/L3 resident).
// - Hash math done in uint32: XOR/mod-2^19 only needs low 19 bits, which
//   uint32 wraparound multiply preserves exactly (all int64 terms in the
//   reference are non-negative). Bit-exact vs the int64 reference.
__global__ __launch_bounds__(256) void HashEncoding_kernel(
    const float* __restrict__ xyz,
    const float* __restrict__ tables,
    float2* __restrict__ out,
    int n_points)
{
    int tid = blockIdx.x * blockDim.x + threadIdx.x;
    int n = tid >> 4;   // point index
    int l = tid & 15;   // level index
    if (n >= n_points) return;

    // 4 points per wave -> these three loads touch ~1-2 cache lines each,
    // broadcast within the wave by L1.
    float x = xyz[n * 3 + 0];
    float y = xyz[n * 3 + 1];
    float z = xyz[n * 3 + 2];

    // res = 16 * 2^l, exact in f32. Single f32 multiply then trunc matches
    // the reference's float32 scale + astype(int64) bit-exactly (inputs >= 0).
    float res = (float)(16u << l);
    unsigned ix = (unsigned)(x * res);
    unsigned iy = (unsigned)(y * res);
    unsigned iz = (unsigned)(z * res);

    unsigned h = (ix ^ (iy * 2654435761u) ^ (iz * 805459861u)) & (TABLE_SIZE - 1u);

    const float2* tbl = (const float2*)tables + ((size_t)l << LOG2_HASHMAP) + h;
    float2 f = *tbl;

    out[(size_t)n * NUM_LEVELS + l] = f;
}

extern "C" void kernel_launch(void* const* d_in, const int* in_sizes, int n_in,
                              void* d_out, int out_size, void* d_ws, size_t ws_size,
                              hipStream_t stream) {
    const float* xyz    = (const float*)d_in[0];
    const float* tables = (const float*)d_in[1];
    float2* out = (float2*)d_out;

    int n_points = in_sizes[0] / 3;
    int total = n_points * NUM_LEVELS;
    int block = 256;
    int grid = (total + block - 1) / block;

    HashEncoding_kernel<<<grid, block, 0, stream>>>(xyz, tables, out, n_points);
}

// Round 2
// 327.659 us; speedup vs baseline: 1.6883x; 1.6883x over previous
//
#include <hip/hip_runtime.h>

#define NUM_LEVELS 16
#define LOG2_HASHMAP 19
#define TABLE_SIZE (1u << LOG2_HASHMAP)

typedef unsigned long long u64;   // opaque 8-byte carrier for float2 payloads

// ---------------- Stage 1: level-major gather into ws[l][n] ----------------
// Block b handles ONE level (l = b / blocks_per_level) and 256 consecutive
// points. Level-major block ordering => dispatcher runs levels roughly
// sequentially, so each XCD's 4 MB L2 holds just the active level's 4 MB
// table (vs 64 MB working set before). Table gathers become ~75% L2 hits
// (cold fill only). ws writes are coalesced and NON-TEMPORAL so the 256 MB
// write stream doesn't evict the table from L2.
__global__ __launch_bounds__(256) void gather_kernel(
    const float* __restrict__ xyz,
    const float* __restrict__ tables,
    u64* __restrict__ ws,
    int n_points, int blocks_per_level)
{
    int b = blockIdx.x;
    int l = b / blocks_per_level;
    int n = (b - l * blocks_per_level) * 256 + threadIdx.x;
    if (n >= n_points) return;

    float x = xyz[n * 3 + 0];
    float y = xyz[n * 3 + 1];
    float z = xyz[n * 3 + 2];

    // res = 16*2^l exact in f32; f32 mul + trunc == reference bit-exactly.
    float res = (float)(16u << l);
    unsigned ix = (unsigned)(x * res);
    unsigned iy = (unsigned)(y * res);
    unsigned iz = (unsigned)(z * res);
    // uint32 wraparound preserves the low 19 bits of the int64 reference math.
    unsigned h = (ix ^ (iy * 2654435761u) ^ (iz * 805459861u)) & (TABLE_SIZE - 1u);

    u64 f = *((const u64*)tables + (((size_t)l << LOG2_HASHMAP) + h));
    __builtin_nontemporal_store(f, ws + (size_t)l * n_points + n);
}

// ---------------- Stage 2: transpose ws[16][N] -> out[N][16] ----------------
// 128 points per block through LDS; both global read and write fully
// coalesced; streaming (non-temporal) on both sides.
__global__ __launch_bounds__(256) void transpose_kernel(
    const u64* __restrict__ ws,
    u64* __restrict__ out,
    int n_points)
{
    __shared__ u64 tile[128][NUM_LEVELS + 1];  // +1 pad: balanced banks both phases
    int n0 = blockIdx.x * 128;

    // Load: iterate 2048 elems with 256 threads; consecutive tids read
    // consecutive addresses within a level row -> coalesced.
    for (int i = threadIdx.x; i < 128 * NUM_LEVELS; i += 256) {
        int l = i >> 7;       // level row
        int n = i & 127;      // point within tile
        int gn = n0 + n;
        u64 v = (gn < n_points)
                  ? __builtin_nontemporal_load(ws + (size_t)l * n_points + gn)
                  : 0ull;
        tile[n][l] = v;
    }
    __syncthreads();

    // Store: out offset = n0*16 + i, consecutive in i -> fully coalesced.
    for (int i = threadIdx.x; i < 128 * NUM_LEVELS; i += 256) {
        int n = i >> 4;
        int l = i & 15;
        if (n0 + n < n_points)
            __builtin_nontemporal_store(tile[n][l], out + (size_t)n0 * NUM_LEVELS + i);
    }
}

// ---------------- Fallback (round-1 kernel) if ws too small ----------------
__global__ __launch_bounds__(256) void fused_kernel(
    const float* __restrict__ xyz,
    const float* __restrict__ tables,
    u64* __restrict__ out,
    int n_points)
{
    int tid = blockIdx.x * blockDim.x + threadIdx.x;
    int n = tid >> 4;
    int l = tid & 15;
    if (n >= n_points) return;
    float x = xyz[n * 3 + 0], y = xyz[n * 3 + 1], z = xyz[n * 3 + 2];
    float res = (float)(16u << l);
    unsigned ix = (unsigned)(x * res);
    unsigned iy = (unsigned)(y * res);
    unsigned iz = (unsigned)(z * res);
    unsigned h = (ix ^ (iy * 2654435761u) ^ (iz * 805459861u)) & (TABLE_SIZE - 1u);
    u64 f = *((const u64*)tables + (((size_t)l << LOG2_HASHMAP) + h));
    out[(size_t)n * NUM_LEVELS + l] = f;
}

extern "C" void kernel_launch(void* const* d_in, const int* in_sizes, int n_in,
                              void* d_out, int out_size, void* d_ws, size_t ws_size,
                              hipStream_t stream) {
    const float* xyz    = (const float*)d_in[0];
    const float* tables = (const float*)d_in[1];

    int n_points = in_sizes[0] / 3;
    size_t ws_needed = (size_t)n_points * NUM_LEVELS * sizeof(u64);

    if (ws_size >= ws_needed) {
        int blocks_per_level = (n_points + 255) / 256;
        int grid1 = blocks_per_level * NUM_LEVELS;
        gather_kernel<<<grid1, 256, 0, stream>>>(
            xyz, tables, (u64*)d_ws, n_points, blocks_per_level);

        int grid2 = (n_points + 127) / 128;
        transpose_kernel<<<grid2, 256, 0, stream>>>(
            (const u64*)d_ws, (u64*)d_out, n_points);
    } else {
        int total = n_points * NUM_LEVELS;
        int grid = (total + 255) / 256;
        fused_kernel<<<grid, 256, 0, stream>>>(xyz, tables, (u64*)d_out, n_points);
    }
}

// Round 3
// 319.083 us; speedup vs baseline: 1.7337x; 1.0269x over previous
//
#include <hip/hip_runtime.h>

#define NUM_LEVELS 16
#define LOG2_HASHMAP 19
#define TABLE_SIZE (1u << LOG2_HASHMAP)

typedef unsigned long long u64;   // opaque 8-byte carrier for float2 payloads

// ---------------- Stage 1: XCD-pinned level-major gather -------------------
// blockIdx.x % 8 == XCD (round-robin dispatch, measured learn_hip m09 /
// T1 swizzle). Pin levels to XCDs: XCD x handles level x first, then x+8.
// Each XCD's 4 MB L2 then holds exactly ONE level's 4 MB table at a time,
// fetched once total (64 MB table traffic instead of 8-XCD x 4 MB x 16 =
// 512 MB duplication). Gathers become local-L2 hits; HBM side is just the
// cold fill + xyz + the non-temporal ws write stream.
__global__ __launch_bounds__(256) void gather_kernel(
    const float* __restrict__ xyz,
    const float* __restrict__ tables,
    u64* __restrict__ ws,
    int n_points, int blocks_per_level)
{
    int b   = blockIdx.x;
    int xcd = b & 7;          // which XCD this block lands on
    int j   = b >> 3;         // sequence index within this XCD
    int phase = (j >= blocks_per_level) ? 1 : 0;   // first or second level
    int l   = xcd + (phase << 3);
    int n   = (j - phase * blocks_per_level) * 256 + threadIdx.x;
    if (n >= n_points) return;

    float x = xyz[n * 3 + 0];
    float y = xyz[n * 3 + 1];
    float z = xyz[n * 3 + 2];

    // res = 16*2^l exact in f32; f32 mul + trunc == reference bit-exactly.
    float res = (float)(16u << l);
    unsigned ix = (unsigned)(x * res);
    unsigned iy = (unsigned)(y * res);
    unsigned iz = (unsigned)(z * res);
    // uint32 wraparound preserves the low 19 bits of the int64 reference math.
    unsigned h = (ix ^ (iy * 2654435761u) ^ (iz * 805459861u)) & (TABLE_SIZE - 1u);

    u64 f = *((const u64*)tables + (((size_t)l << LOG2_HASHMAP) + h));
    __builtin_nontemporal_store(f, ws + (size_t)l * n_points + n);
}

// ---------------- Stage 2: transpose ws[16][N] -> out[N][16] ----------------
// Measured 5.6 TB/s (near streaming ceiling) — unchanged from round 2.
__global__ __launch_bounds__(256) void transpose_kernel(
    const u64* __restrict__ ws,
    u64* __restrict__ out,
    int n_points)
{
    __shared__ u64 tile[128][NUM_LEVELS + 1];  // +1 pad: balanced banks both phases
    int n0 = blockIdx.x * 128;

    for (int i = threadIdx.x; i < 128 * NUM_LEVELS; i += 256) {
        int l = i >> 7;       // level row
        int n = i & 127;      // point within tile
        int gn = n0 + n;
        u64 v = (gn < n_points)
                  ? __builtin_nontemporal_load(ws + (size_t)l * n_points + gn)
                  : 0ull;
        tile[n][l] = v;
    }
    __syncthreads();

    for (int i = threadIdx.x; i < 128 * NUM_LEVELS; i += 256) {
        int n = i >> 4;
        int l = i & 15;
        if (n0 + n < n_points)
            __builtin_nontemporal_store(tile[n][l], out + (size_t)n0 * NUM_LEVELS + i);
    }
}

// ---------------- Fallback (round-1 kernel) if ws too small ----------------
__global__ __launch_bounds__(256) void fused_kernel(
    const float* __restrict__ xyz,
    const float* __restrict__ tables,
    u64* __restrict__ out,
    int n_points)
{
    int tid = blockIdx.x * blockDim.x + threadIdx.x;
    int n = tid >> 4;
    int l = tid & 15;
    if (n >= n_points) return;
    float x = xyz[n * 3 + 0], y = xyz[n * 3 + 1], z = xyz[n * 3 + 2];
    float res = (float)(16u << l);
    unsigned ix = (unsigned)(x * res);
    unsigned iy = (unsigned)(y * res);
    unsigned iz = (unsigned)(z * res);
    unsigned h = (ix ^ (iy * 2654435761u) ^ (iz * 805459861u)) & (TABLE_SIZE - 1u);
    u64 f = *((const u64*)tables + (((size_t)l << LOG2_HASHMAP) + h));
    out[(size_t)n * NUM_LEVELS + l] = f;
}

extern "C" void kernel_launch(void* const* d_in, const int* in_sizes, int n_in,
                              void* d_out, int out_size, void* d_ws, size_t ws_size,
                              hipStream_t stream) {
    const float* xyz    = (const float*)d_in[0];
    const float* tables = (const float*)d_in[1];

    int n_points = in_sizes[0] / 3;
    size_t ws_needed = (size_t)n_points * NUM_LEVELS * sizeof(u64);

    if (ws_size >= ws_needed) {
        int blocks_per_level = (n_points + 255) / 256;
        int grid1 = blocks_per_level * NUM_LEVELS;   // 16*bpl, divisible by 8
        gather_kernel<<<grid1, 256, 0, stream>>>(
            xyz, tables, (u64*)d_ws, n_points, blocks_per_level);

        int grid2 = (n_points + 127) / 128;
        transpose_kernel<<<grid2, 256, 0, stream>>>(
            (const u64*)d_ws, (u64*)d_out, n_points);
    } else {
        int total = n_points * NUM_LEVELS;
        int grid = (total + 255) / 256;
        fused_kernel<<<grid, 256, 0, stream>>>(xyz, tables, (u64*)d_out, n_points);
    }
}